// Round 5
// baseline (73.139 us; speedup 1.0000x reference)
//
#include <hip/hip_runtime.h>
#include <hip/hip_bf16.h>
#include <math.h>

#define NDIM 4096
#define MDIM 4096
#define LDIM 512
#define KDIM 1024
#define NT2  32     // K-tiles of BK=32

typedef short bf16x8 __attribute__((ext_vector_type(8)));
typedef float f32x4 __attribute__((ext_vector_type(4)));

#define GLOBAL_AS __attribute__((address_space(1)))
#define LDS_AS __attribute__((address_space(3)))

__device__ __align__(16) __hip_bfloat16 g_A[(size_t)NDIM * KDIM];
__device__ __align__(16) __hip_bfloat16 g_B[(size_t)MDIM * KDIM];

__device__ __forceinline__ void gload_lds16(void* lds, const void* g) {
  __builtin_amdgcn_global_load_lds((const GLOBAL_AS void*)g, (LDS_AS void*)lds, 16, 0, 0);
}

// ---------------------------------------------------------------------------
// scale_kernel: ws[0] = |var| / sum_l exp(-0.5*lam_l)   (1 block, 512 thr)
// ---------------------------------------------------------------------------
__global__ __launch_bounds__(512) void scale_kernel(const float* __restrict__ lam,
                                                    const float* __restrict__ var,
                                                    float* __restrict__ ws) {
  int l = threadIdx.x;
  float v = expf(-0.5f * lam[l]);
  #pragma unroll
  for (int off = 32; off > 0; off >>= 1) v += __shfl_down(v, off, 64);
  __shared__ float red[8];
  if ((l & 63) == 0) red[l >> 6] = v;
  __syncthreads();
  if (l == 0) {
    float t = 0.f;
    #pragma unroll
    for (int i = 0; i < 8; ++i) t += red[i];
    ws[0] = fabsf(var[0]) / t;
  }
}

// ---------------------------------------------------------------------------
// Phase kernel: 256 threads, each handles 2 adjacent l's -> 4B packed stores.
// A[n][l] = s*w_l*cos(px), A[n][l+512] = s*w_l*sin(px); B rows: wgt=1.
// ---------------------------------------------------------------------------
__global__ __launch_bounds__(256) void phase_kernel(const float* __restrict__ x,
                                                    const float* __restrict__ y,
                                                    const float* __restrict__ freqs,
                                                    const float* __restrict__ lam,
                                                    const float* __restrict__ ws) {
  int t = threadIdx.x;          // 0..255
  int l0 = 2 * t, l1 = 2 * t + 1;
  int r = blockIdx.x;           // 0..8191
  float s = ws[0];
  float w0 = expf(-0.5f * lam[l0]);
  float w1 = expf(-0.5f * lam[l1]);
  float a0 = freqs[l0 * 3 + 0], a1 = freqs[l0 * 3 + 1], a2 = freqs[l0 * 3 + 2];
  float b0 = freqs[l1 * 3 + 0], b1 = freqs[l1 * 3 + 1], b2 = freqs[l1 * 3 + 2];
  bool isA = (r < NDIM);
  int rr = isA ? r : (r - NDIM);
  const float* p = isA ? (x + (size_t)rr * 3) : (y + (size_t)rr * 3);
  float p0 = p[0], p1 = p[1], p2 = p[2];
  float px0 = p0 * a0 + p1 * a1 + p2 * a2;
  float px1 = p0 * b0 + p1 * b1 + p2 * b2;
  float sn0, cs0, sn1, cs1;
  __sincosf(px0, &sn0, &cs0);
  __sincosf(px1, &sn1, &cs1);
  float g0 = isA ? (w0 * s) : 1.0f;
  float g1 = isA ? (w1 * s) : 1.0f;
  __hip_bfloat16* dst = (isA ? g_A : g_B) + (size_t)rr * KDIM;
  __hip_bfloat162 cpair, spair;
  cpair.x = __float2bfloat16(g0 * cs0); cpair.y = __float2bfloat16(g1 * cs1);
  spair.x = __float2bfloat16(g0 * sn0); spair.y = __float2bfloat16(g1 * sn1);
  *(__hip_bfloat162*)&dst[l0]        = cpair;
  *(__hip_bfloat162*)&dst[LDIM + l0] = spair;
}

// ---------------------------------------------------------------------------
// GEMM: C[4096][4096] f32 = A @ B^T, bf16, K=1024.
// 256x128 tile, BK=32, 4 waves (2Mx2N, wave-tile 128x64), 3-deep LDS buffers
// (72 KiB -> 2 blocks/CU), stage-ahead-2 with counted vmcnt(6), swizzled LDS,
// 1 barrier/iter, setprio around the 32-MFMA cluster.
// ---------------------------------------------------------------------------
__global__ __launch_bounds__(256, 2) void gemm_kernel(float* __restrict__ C) {
  __shared__ __align__(16) short Al[3][256 * 32];   // 3 x 16 KB
  __shared__ __align__(16) short Bl[3][128 * 32];   // 3 x  8 KB

  int bid = blockIdx.x;                   // 0..511
  int swz = (bid & 7) * 64 + (bid >> 3);  // XCD swizzle (512 % 8 == 0)
  int brow = (swz >> 5) * 256;            // 16 row strips
  int bcol = (swz & 31) * 128;            // 32 col strips

  int tid  = threadIdx.x;
  int lane = tid & 63;
  int wid  = tid >> 6;                    // 0..3
  int wm   = wid >> 1;                    // 0..1 -> rows wm*128..+127
  int wn   = wid & 1;                     // 0..1 -> cols wn*64..+63

  // ds_read offsets (swizzled: byte ^= ((row>>1)&3)<<4 within 64B rows)
  int fr   = lane & 15;
  int cs_  = ((lane >> 4) * 16) ^ (((fr >> 1) & 3) << 4);
  int offA[8], offB[4];
  #pragma unroll
  for (int m = 0; m < 8; ++m) offA[m] = (wm * 128 + m * 16 + fr) * 64 + cs_;
  #pragma unroll
  for (int n = 0; n < 4; ++n) offB[n] = (wn * 64 + n * 16 + fr) * 64 + cs_;

  // staging constants (pre-swizzled global source; LDS dest linear)
  int scb  = ((tid & 3) * 16) ^ (((tid >> 3) & 3) << 4);   // byte in 64B k-row
  const short* gA = (const short*)g_A + (size_t)(brow + (tid >> 2)) * KDIM + scb / 2;
  const short* gB = (const short*)g_B + (size_t)(bcol + (tid >> 2)) * KDIM + scb / 2;

  f32x4 acc[8][4] = {};
  bf16x8 a0, a1, a2, a3, a4, a5, a6, a7, b0, b1, b2, b3;

  // Stage tile T1 into buffer SB: A 4 issues (64-row chunks), B 2 issues.
#define STAGE(SB, T1)                                                        \
  {                                                                          \
    char* dA = (char*)Al + (SB) * 16384 + tid * 16;                          \
    const short* sA = gA + (T1) * 32;                                        \
    gload_lds16(dA,         sA);                                             \
    gload_lds16(dA + 4096,  sA + (size_t)64 * KDIM);                         \
    gload_lds16(dA + 8192,  sA + (size_t)128 * KDIM);                        \
    gload_lds16(dA + 12288, sA + (size_t)192 * KDIM);                        \
    char* dB = (char*)Bl + (SB) * 8192 + tid * 16;                           \
    const short* sB = gB + (T1) * 32;                                        \
    gload_lds16(dB,        sB);                                              \
    gload_lds16(dB + 4096, sB + (size_t)64 * KDIM);                          \
  }

#define VMCNT(N) asm volatile("s_waitcnt vmcnt(" #N ")" ::: "memory")
#define LGKM0    asm volatile("s_waitcnt lgkmcnt(0)" ::: "memory")
#define SCHED0   __builtin_amdgcn_sched_barrier(0)
#define BAR      __builtin_amdgcn_s_barrier()

#define READS(CUR)                                                           \
  { const char* Ab_ = (const char*)Al + (CUR) * 16384;                       \
    const char* Bb_ = (const char*)Bl + (CUR) * 8192;                        \
    a0 = *(const bf16x8*)(Ab_ + offA[0]);                                    \
    a1 = *(const bf16x8*)(Ab_ + offA[1]);                                    \
    a2 = *(const bf16x8*)(Ab_ + offA[2]);                                    \
    a3 = *(const bf16x8*)(Ab_ + offA[3]);                                    \
    a4 = *(const bf16x8*)(Ab_ + offA[4]);                                    \
    a5 = *(const bf16x8*)(Ab_ + offA[5]);                                    \
    a6 = *(const bf16x8*)(Ab_ + offA[6]);                                    \
    a7 = *(const bf16x8*)(Ab_ + offA[7]);                                    \
    b0 = *(const bf16x8*)(Bb_ + offB[0]);                                    \
    b1 = *(const bf16x8*)(Bb_ + offB[1]);                                    \
    b2 = *(const bf16x8*)(Bb_ + offB[2]);                                    \
    b3 = *(const bf16x8*)(Bb_ + offB[3]); }

#define MFMA4(I, AF)                                                                  \
  acc[I][0] = __builtin_amdgcn_mfma_f32_16x16x32_bf16(AF, b0, acc[I][0], 0, 0, 0);    \
  acc[I][1] = __builtin_amdgcn_mfma_f32_16x16x32_bf16(AF, b1, acc[I][1], 0, 0, 0);    \
  acc[I][2] = __builtin_amdgcn_mfma_f32_16x16x32_bf16(AF, b2, acc[I][2], 0, 0, 0);    \
  acc[I][3] = __builtin_amdgcn_mfma_f32_16x16x32_bf16(AF, b3, acc[I][3], 0, 0, 0);

#define MFMA32                                                               \
  __builtin_amdgcn_s_setprio(1);                                             \
  MFMA4(0, a0) MFMA4(1, a1) MFMA4(2, a2) MFMA4(3, a3)                        \
  MFMA4(4, a4) MFMA4(5, a5) MFMA4(6, a6) MFMA4(7, a7)                        \
  __builtin_amdgcn_s_setprio(0);

  // ---- prologue: stage tiles 0,1 (12 loads); wait tile 0; barrier ----
  STAGE(0, 0);
  STAGE(1, 1);
  VMCNT(6);
  BAR;

  // ---- main loop t=0..29: stage(t+2) into freed buffer, compute t ----
  int cur = 0, sb = 2;
  for (int t = 0; t < 30; ++t) {
    STAGE(sb, t + 2);            // buf (t+2)%3 freed by end-of-iter t-1 BAR
    READS(cur);
    LGKM0; SCHED0;
    MFMA32;
    VMCNT(6);                    // tiles {t+2} in flight (6); t+1 landed
    BAR;
    cur = (cur == 2) ? 0 : cur + 1;
    sb  = (sb == 2) ? 0 : sb + 1;
  }
  // t = 30: no stage; wait tile 31
  READS(cur);
  LGKM0; SCHED0;
  MFMA32;
  VMCNT(0);
  BAR;
  cur = (cur == 2) ? 0 : cur + 1;
  // t = 31
  READS(cur);
  LGKM0; SCHED0;
  MFMA32;

  // ---- epilogue: C/D layout col=lane&15, row=(lane>>4)*4+j ----
  int crow = brow + wm * 128 + (lane >> 4) * 4;
  int ccol = bcol + wn * 64 + (lane & 15);
  #pragma unroll
  for (int mi = 0; mi < 8; ++mi)
    #pragma unroll
    for (int n = 0; n < 4; ++n)
      #pragma unroll
      for (int j = 0; j < 4; ++j)
        C[(size_t)(crow + mi * 16 + j) * MDIM + (ccol + n * 16)] = acc[mi][n][j];
}

extern "C" void kernel_launch(void* const* d_in, const int* in_sizes, int n_in,
                              void* d_out, int out_size, void* d_ws, size_t ws_size,
                              hipStream_t stream) {
  const float* x     = (const float*)d_in[0];
  const float* y     = (const float*)d_in[1];
  const float* freqs = (const float*)d_in[2];
  const float* lam   = (const float*)d_in[3];
  const float* var   = (const float*)d_in[4];
  float* out = (float*)d_out;
  float* ws  = (float*)d_ws;

  hipLaunchKernelGGL(scale_kernel, dim3(1), dim3(512), 0, stream, lam, var, ws);
  hipLaunchKernelGGL(phase_kernel, dim3(NDIM + MDIM), dim3(256), 0, stream,
                     x, y, freqs, lam, ws);
  hipLaunchKernelGGL(gemm_kernel, dim3((NDIM / 256) * (MDIM / 128)), dim3(256), 0, stream,
                     out);
}